// Round 3
// 879.162 us; speedup vs baseline: 1.0078x; 1.0078x over previous
//
#include <hip/hip_runtime.h>
#include <float.h>

// APoT quantizer forward: out = a * nearest_level(clip(x/a, -1, 1)), a = |alpha|+1e-8.
// Reference nearest: ir = clip(searchsorted(levels, xn, 'left'), 0, L-1); il = ir-1 clipped;
//                    choose right iff |xn-left| > |right-xn| (tie -> left).
//
// Fast path (L == 511): levels are symmetric. Fold sign: search u=|xn| over the 256
// nonnegative levels P[j] = levels[255+j]. For xn<0, searchsorted-left on the signed
// array maps exactly to "go right iff e <= u" on the folded side, which equals
// "e < nextafter(u)" (one uint add), and the tie rule flips > to >=. Output sign is
// reapplied at the end (a*(-v) == -(a*v) exactly in IEEE).
// Tree over P[1..255] (P[0]=0 is the init left-neighbor): height 8.
//   depths 0..2 (nodes 1..7)  -> registers + cndmask chains (no LDS)
//   depths 3..7 (nodes 8..255)-> LDS Eytzinger, 5 ds_read_b32 per element
// When a == 1.0f (this workload: alpha=1, 1+1e-8 rounds to 1.0f), x/a == x bit-exactly,
// so a uniform branch selects a division-free loop. All paths bit-exact vs reference
// (only possible deviation is -0.0 vs +0.0, canonicalized by the final +0.0f).
//
// NOTE: plain vector loads (not __builtin_nontemporal_load) — the NT-load variant was
// the only round-0-unverified construct in the twice-failed submission; reads are
// streaming anyway, so the hint was worth ~0.

typedef float floatx4 __attribute__((ext_vector_type(4)));

// ---------------- fast path: L == 511 ----------------

template<bool AONE>
__device__ __forceinline__ float apot_fold(
    float xi, float a, const float* __restrict__ eyt, float zl,
    float e1, float e2, float e3, float e4, float e5, float e6, float e7)
{
    float xn = AONE ? xi : (xi / a);            // IEEE div only on generic path
    xn = fminf(fmaxf(xn, -1.0f), 1.0f);
    bool neg = xn < 0.0f;                       // -0.0 takes the positive path
    float u  = fabsf(xn);
    // strict-< with us == (neg ? nextafter(u,+inf) : u) implements e<=u for neg lanes
    float us = __uint_as_float(__float_as_uint(u) + (neg ? 1u : 0u));

    float lft = zl;        // P[0] = 0.0f: left neighbor when nothing smaller passed
    float rgt = FLT_MAX;   // right neighbor when u_s above all levels (only u=1, neg)

    // depth 0..2 in registers
    bool g0 = e1 < us;  lft = g0 ? e1 : lft;  rgt = g0 ? rgt : e1;
    float ea = g0 ? e3 : e2;
    bool g1 = ea < us;  lft = g1 ? ea : lft;  rgt = g1 ? rgt : ea;
    float t0 = g1 ? e5 : e4;
    float t1 = g1 ? e7 : e6;
    float eb = g0 ? t1 : t0;
    bool g2 = eb < us;  lft = g2 ? eb : lft;  rgt = g2 ? rgt : eb;

    // depth 3..7 in LDS
    int idx = 8 + (g0 ? 4 : 0) + (g1 ? 2 : 0) + (g2 ? 1 : 0);
    #pragma unroll
    for (int s = 0; s < 5; ++s) {
        float e = eyt[idx];
        bool g = e < us;
        lft = g ? e : lft;
        rgt = g ? rgt : e;
        idx = 2 * idx + (g ? 1 : 0);
    }

    float dl = u - lft;                          // exact, >= 0 (lft <= u)
    float dr = rgt - u;                          // exact, >= 0 (rgt >= u)
    bool cr = neg ? (dl >= dr) : (dl > dr);      // folded tie rule flips for neg
    float mag = cr ? rgt : lft;
    float res = AONE ? mag : (a * mag);
    res = neg ? -res : res;
    return res + 0.0f;                           // canonicalize -0.0 -> +0.0
}

template<bool AONE>
__device__ __forceinline__ void apot_loop_511(
    const float* __restrict__ x, float* __restrict__ out,
    long long n, long long n4, float a, float zl,
    const float* __restrict__ eyt,
    float e1, float e2, float e3, float e4, float e5, float e6, float e7)
{
    long long tid = (long long)blockIdx.x * blockDim.x + threadIdx.x;
    long long stride = (long long)gridDim.x * blockDim.x;
    const floatx4* __restrict__ x4 = (const floatx4*)x;
    floatx4* __restrict__ o4 = (floatx4*)out;
    for (long long t = tid; t < n4; t += stride) {
        floatx4 v = x4[t];
        floatx4 ov;
        ov.x = apot_fold<AONE>(v.x, a, eyt, zl, e1, e2, e3, e4, e5, e6, e7);
        ov.y = apot_fold<AONE>(v.y, a, eyt, zl, e1, e2, e3, e4, e5, e6, e7);
        ov.z = apot_fold<AONE>(v.z, a, eyt, zl, e1, e2, e3, e4, e5, e6, e7);
        ov.w = apot_fold<AONE>(v.w, a, eyt, zl, e1, e2, e3, e4, e5, e6, e7);
        __builtin_nontemporal_store(ov, &o4[t]);
    }
    for (long long t = n4 * 4 + tid; t < n; t += stride) {  // empty for this shape
        out[t] = apot_fold<AONE>(x[t], a, eyt, zl, e1, e2, e3, e4, e5, e6, e7);
    }
}

__global__ __launch_bounds__(256) void apot_kernel_511(
    const float* __restrict__ x,
    const float* __restrict__ alpha,
    const float* __restrict__ levels,
    float* __restrict__ out,
    long long n, long long n4)
{
    // Eytzinger over V[0..254] = P[1..255] = levels[256..510]; nodes 1..255, eyt[0] unused
    __shared__ float eyt[256];
    for (int i = threadIdx.x + 1; i < 256; i += blockDim.x) {
        int d = 31 - __clz(i);                      // depth 0..7
        int pos = i - (1 << d);
        int srt = pos * (1 << (8 - d)) + (1 << (7 - d)) - 1;   // 0..254
        eyt[i] = levels[256 + srt];
    }
    __syncthreads();

    float a  = fabsf(alpha[0]) + 1e-8f;
    float zl = levels[255];                         // +0.0f
    float e1 = eyt[1], e2 = eyt[2], e3 = eyt[3], e4 = eyt[4],
          e5 = eyt[5], e6 = eyt[6], e7 = eyt[7];

    if (a == 1.0f) {   // uniform branch; x/1.0 == x and 1.0*v == v bit-exactly
        apot_loop_511<true >(x, out, n, n4, a, zl, eyt, e1, e2, e3, e4, e5, e6, e7);
    } else {
        apot_loop_511<false>(x, out, n, n4, a, zl, eyt, e1, e2, e3, e4, e5, e6, e7);
    }
}

// ---------------- generic fallback (any L <= 511): previous proven kernel ----------------

#define TREE_H 9
#define NNODES (1 << TREE_H)

__device__ __forceinline__ float apot_one(float xi, float a,
                                          const float* __restrict__ eyt,
                                          float lev0, float levmax) {
    float xn = xi / a;
    xn = fminf(fmaxf(xn, -1.0f), 1.0f);
    int idx = 1;
    float lft = lev0;
    float rgt = levmax;
    #pragma unroll
    for (int s = 0; s < TREE_H; ++s) {
        float e = eyt[idx];
        bool go_r = e < xn;
        lft = go_r ? e : lft;
        rgt = go_r ? rgt : e;
        idx = 2 * idx + (go_r ? 1 : 0);
    }
    float d_l = fabsf(xn - lft);
    float d_r = fabsf(rgt - xn);
    return a * ((d_l > d_r) ? rgt : lft);
}

__global__ __launch_bounds__(256) void apot_kernel(
    const float* __restrict__ x,
    const float* __restrict__ alpha,
    const float* __restrict__ levels,
    float* __restrict__ out,
    long long n, long long n4, int L)
{
    __shared__ float eyt[NNODES];
    for (int i = threadIdx.x + 1; i < NNODES; i += blockDim.x) {
        int d = 31 - __clz(i);
        int pos = i - (1 << d);
        int srt = pos * (1 << (TREE_H - d)) + (1 << (TREE_H - 1 - d)) - 1;
        eyt[i] = (srt < L) ? levels[srt] : FLT_MAX;
    }
    __syncthreads();

    float a = fabsf(alpha[0]) + 1e-8f;
    float lev0 = levels[0];
    float levmax = levels[L - 1];

    long long tid = (long long)blockIdx.x * blockDim.x + threadIdx.x;
    long long stride = (long long)gridDim.x * blockDim.x;

    const floatx4* __restrict__ x4 = (const floatx4*)x;
    floatx4* __restrict__ o4 = (floatx4*)out;
    for (long long t = tid; t < n4; t += stride) {
        floatx4 v = x4[t];
        floatx4 ov;
        ov.x = apot_one(v.x, a, eyt, lev0, levmax);
        ov.y = apot_one(v.y, a, eyt, lev0, levmax);
        ov.z = apot_one(v.z, a, eyt, lev0, levmax);
        ov.w = apot_one(v.w, a, eyt, lev0, levmax);
        __builtin_nontemporal_store(ov, &o4[t]);
    }
    for (long long t = n4 * 4 + tid; t < n; t += stride) {
        out[t] = apot_one(x[t], a, eyt, lev0, levmax);
    }
}

extern "C" void kernel_launch(void* const* d_in, const int* in_sizes, int n_in,
                              void* d_out, int out_size, void* d_ws, size_t ws_size,
                              hipStream_t stream) {
    const float* x      = (const float*)d_in[0];
    const float* alpha  = (const float*)d_in[1];
    const float* levels = (const float*)d_in[2];
    float* out = (float*)d_out;

    long long n  = (long long)out_size;
    long long n4 = n >> 2;
    int L = in_sizes[2];

    const int block = 256;
    long long want = (n4 + block - 1) / block;
    if (want < 1) want = 1;
    int grid = (int)(want < 8192 ? want : 8192);

    if (L == 511) {
        apot_kernel_511<<<grid, block, 0, stream>>>(x, alpha, levels, out, n, n4);
    } else {
        apot_kernel<<<grid, block, 0, stream>>>(x, alpha, levels, out, n, n4, L);
    }
}